// Round 8
// baseline (149.411 us; speedup 1.0000x reference)
//
#include <hip/hip_runtime.h>
#include <stdint.h>

// Round 18 (= r17 resubmitted; r17 bench died on container acquisition, not
// on the kernel): r15 (best measured, 143.1 us) + nontemporal on the
// now-full-line stores — single-variable A/B isolating NT (r16 bundled NT
// with the 2D map, which is independently null-to-negative).
// Theory: plain stores stream 134 MB of output through L2, evicting the
// 4.3 MB Q image (barely exceeds one XCD's 4 MiB L2 even alone) -> HBM
// re-fetches on the gather side. NT bypasses L2 for output; Q stays hot.
// Stores are 1 KB/wave contiguous full lines (r15 layout), so NT cannot
// trigger partial-line RMW (the r10-r14 defect).
//
// Compute = r15 byte-identical: quad-gather, zero-seg, segsafe de-clamp,
// pipelined loads, 2x4-px segments per thread.
// fp32 in / fp32 out. gt_up[y,x] == gt[y>>3, x>>3] (never materialized).

typedef float vfloat4 __attribute__((ext_vector_type(4)));

constexpr int BATCH = 8;
constexpr int HI = 128, WI = 256;
constexpr int HO = 1024, WO = 2048;
constexpr size_t NPIX = (size_t)BATCH * HO * WO;   // 16777216 per output

// Quad image: Q[y+1][x+1] = (P[y][x], P[y][x+1], P[y+1][x], P[y+1][x+1]),
// P = zero-padded gt. Row index cy0+1 in [0,129], col cx0+1 in [0,257].
constexpr int QH = HI + 2;
constexpr int QW = WI + 2;
constexpr size_t QIMG = (size_t)QH * QW;           // quads per image

__global__ __launch_bounds__(256) void pad4_kernel(
    const float* __restrict__ gt, vfloat4* __restrict__ Q)
{
    const int i = blockIdx.x * 256 + threadIdx.x;  // over BATCH*QIMG
    if (i >= (int)(BATCH * QIMG)) return;
    const int b = i / (int)QIMG;
    const int r = i - b * (int)QIMG;
    const int y = r / QW - 1;                      // [-1, HI]
    const int x = r - (r / QW) * QW - 1;           // [-1, WI]
    const float* __restrict__ g = gt + (size_t)b * (HI * WI);
    auto val = [&](int yy, int xx) -> float {
        return (yy >= 0 && yy < HI && xx >= 0 && xx < WI)
                   ? g[yy * WI + xx] : 0.0f;
    };
    vfloat4 q = { val(y, x), val(y, x + 1), val(y + 1, x), val(y + 1, x + 1) };
    Q[i] = q;
}

__global__ __launch_bounds__(256) void stn_kernel(
    const float* __restrict__ gt,     // [B, HI, WI] (boxy path)
    const float* __restrict__ theta,  // [B, 6]
    const vfloat4* __restrict__ Q,    // quad images in d_ws
    float* __restrict__ out)          // [2, B, HO, WO] f32
{
    const int row = blockIdx.x;            // b*HO + h
    const int b = row >> 10;
    const int h = row & (HO - 1);
    const int t = threadIdx.x;

    const float* tb = theta + b * 6;
    const float t0 = tb[0], t1 = tb[1], t2 = tb[2];
    const float t3 = tb[3], t4 = tb[4], t5 = tb[5];
    const float* __restrict__ gtb = gt + b * (HI * WI);
    // Pre-offset so index is cy0*QW + cx0 (pad ring at cy0=-1 / cx0=-1 ok).
    const vfloat4* __restrict__ Qb = Q + (size_t)b * QIMG + QW + 1;

    const float ys = (h + 0.5f) * (2.0f / (float)HO) - 1.0f;
    const float dix = t0;
    const float diy = 0.5f * t3;

    // boxy y-blend pieces (uniform over the row, independent of column):
    const float gy2 = t4 * ys + t5;
    const float iyy = ((gy2 + 1.0f) * (float)HO - 1.0f) * 0.5f;
    const float fyy = floorf(iyy);
    const float wyy = iyy - fyy;
    const float vy0 = (fyy >= 0.0f && fyy <= (float)(HO - 1)) ? 1.0f : 0.0f;
    const float vy1 = (fyy >= -1.0f && fyy <= (float)(HO - 2)) ? 1.0f : 0.0f;
    const int y0 = ((int)fminf(fmaxf(fyy,        0.0f), (float)(HO - 1))) >> 3;
    const int y1 = ((int)fminf(fmaxf(fyy + 1.0f, 0.0f), (float)(HO - 1))) >> 3;
    const float wA = (1.0f - wyy) * vy0;
    const float wB = wyy * vy1;

    float* const outrow  = out + (size_t)row * WO;
    float* const outrowy = out + NPIX + (size_t)row * WO;

#pragma unroll
    for (int s = 0; s < 2; ++s) {
        const int w0s = (s << 10) + (t << 2);   // 4-px segment base column

        // ---- boxy: one scalar per 4-px group (group never straddles a cell) ----
        {
            const int cell = w0s >> 3;
            const float s0 = gtb[y0 * WI + cell];
            const float s1 = gtb[y1 * WI + cell];
            const float byv = s0 * wA + s1 * wB;
            const vfloat4 vb = {byv, byv, byv, byv};
            __builtin_nontemporal_store(
                vb, reinterpret_cast<vfloat4*>(outrowy + w0s));  // 1KB/wave line
        }

        // ---- box: 4 px bilinear via one quad load each ----
        const float xn0 = (w0s + 0.5f) * (2.0f / (float)WO) - 1.0f;
        const float gx0 = t0 * xn0 + (t1 * ys + t2);
        const float gy0 = t3 * xn0 + (t4 * ys + t5);
        const float ix0 = ((gx0 + 1.0f) * (float)WO - 1.0f) * 0.5f;
        const float iy0 = ((gy0 + 1.0f) * (float)HO - 1.0f) * 0.5f;

        const float ixe = ix0 + 3.0f * dix;
        const float iye = iy0 + 3.0f * diy;
        const float ixmin = fminf(ix0, ixe), ixmax = fmaxf(ix0, ixe);
        const float iymin = fminf(iy0, iye), iymax = fmaxf(iy0, iye);
        const bool segzero = (ixmax < -1.0f) || (ixmin >= (float)WO) ||
                             (iymax < -1.0f) || (iymin >= (float)HO);
        const bool segsafe = (ixmin >= -1.0f) && (ixmax < (float)WO) &&
                             (iymin >= -1.0f) && (iymax < (float)HO);

        float px[4];
        if (segzero) {
#pragma unroll
            for (int p = 0; p < 4; ++p) px[p] = 0.0f;
        } else if (segsafe) {
            // No clamps: xi in [-1, WO-1], shifts land in [-1,WI]/[-1,HI];
            // pad ring supplies zeros.
            vfloat4 q[4];
            float wx[4], wy[4];
            bool cxe[4], cye[4];
#pragma unroll
            for (int p = 0; p < 4; ++p) {
                const float ixp = fmaf((float)p, dix, ix0);
                const float iyp = fmaf((float)p, diy, iy0);
                const float fx = floorf(ixp), fy = floorf(iyp);
                wx[p] = ixp - fx;  wy[p] = iyp - fy;
                const int xi = (int)fx, yi = (int)fy;
                const int cx0 = xi >> 3;
                const int cx1 = (xi + 1) >> 3;
                const int cy0 = yi >> 3;
                const int cy1 = (yi + 1) >> 3;
                cxe[p] = (cx1 == cx0);
                cye[p] = (cy1 == cy0);
                q[p] = Qb[cy0 * QW + cx0];
            }
#pragma unroll
            for (int p = 0; p < 4; ++p) {
                const float a  = q[p].x;
                const float bb = cxe[p] ? q[p].x : q[p].y;   // P[cy0][cx1]
                const float c  = cye[p] ? q[p].x : q[p].z;   // P[cy1][cx0]
                const float dl = cxe[p] ? q[p].z : q[p].w;
                const float d  = cye[p] ? bb     : dl;       // P[cy1][cx1]
                const float h0 = fmaf(wx[p], bb - a, a);
                const float h1 = fmaf(wx[p], d - c,  c);
                px[p] = fmaf(wy[p], h1 - h0, h0);
            }
        } else {
            // General clamped path (segment straddles a boundary) — r12 logic.
            float ix = ix0, iy = iy0;
#pragma unroll
            for (int p = 0; p < 4; ++p) {
                const float fx = floorf(ix), fy = floorf(iy);
                const float wx = ix - fx,    wy = iy - fy;
                const int xi = (int)fx, yi = (int)fy;    // cvt saturates at extremes
                const int cx0 = min(max(xi >> 3,       -1), WI);
                const int cx1 = min(max((xi + 1) >> 3, -1), WI);
                const int cy0 = min(max(yi >> 3,       -1), HI);
                const int cy1 = min(max((yi + 1) >> 3, -1), HI);
                const vfloat4 q = Qb[cy0 * QW + cx0];
                const bool cxe = (cx1 == cx0);
                const bool cye = (cy1 == cy0);
                const float a  = q.x;
                const float bb = cxe ? q.x : q.y;        // P[cy0][cx1]
                const float c  = cye ? q.x : q.z;        // P[cy1][cx0]
                const float dl = cxe ? q.z : q.w;
                const float d  = cye ? bb  : dl;         // P[cy1][cx1]
                const float h0 = fmaf(wx, bb - a, a);
                const float h1 = fmaf(wx, d - c,  c);
                px[p] = fmaf(wy, h1 - h0, h0);
                ix += dix; iy += diy;
            }
        }
        const vfloat4 v = {px[0], px[1], px[2], px[3]};
        __builtin_nontemporal_store(
            v, reinterpret_cast<vfloat4*>(outrow + w0s));     // 1KB/wave line
    }
}

extern "C" void kernel_launch(void* const* d_in, const int* in_sizes, int n_in,
                              void* d_out, int out_size, void* d_ws, size_t ws_size,
                              hipStream_t stream) {
    const float* gt    = (const float*)d_in[0];
    const float* theta = (const float*)d_in[1];
    float* out = (float*)d_out;
    vfloat4* Q = (vfloat4*)d_ws;   // 8*130*258*16 B ~= 4.3 MB << ws_size

    const int qN = (int)(BATCH * QIMG);
    pad4_kernel<<<(qN + 255) / 256, 256, 0, stream>>>(gt, Q);
    stn_kernel<<<BATCH * HO, 256, 0, stream>>>(gt, theta, Q, out);
}

// Round 9
// 144.300 us; speedup vs baseline: 1.0354x; 1.0354x over previous
//
#include <hip/hip_runtime.h>
#include <stdint.h>

// Round 19: REVERT to r15 verbatim — the best-measured configuration
// (143.1 us). r18's single-variable A/B showed nontemporal costs +6 us
// vs plain stores (and r16 showed the 2D lane map is null-to-negative).
// r15 = quad-gather + zero-seg + segsafe de-clamp + pipelined loads +
// 2x4-px segments per thread with 1 KB/wave CONTIGUOUS full-line plain
// stores (the store-coverage fix that bought -27 us in r15).
//
// Ledger: loads instr-count/locality/latency all null (r12/r13/r14/r16);
// store line-coverage the only real lever (r15); NT negative (r16/r18).
// stn ~= 30 us vs ~22-24 us pure-write floor; window dominated by harness
// poison fills (~110 us). Expect dur ~= 143 +/- 3.
// fp32 in / fp32 out. gt_up[y,x] == gt[y>>3, x>>3] (never materialized).

typedef float vfloat4 __attribute__((ext_vector_type(4)));

constexpr int BATCH = 8;
constexpr int HI = 128, WI = 256;
constexpr int HO = 1024, WO = 2048;
constexpr size_t NPIX = (size_t)BATCH * HO * WO;   // 16777216 per output

// Quad image: Q[y+1][x+1] = (P[y][x], P[y][x+1], P[y+1][x], P[y+1][x+1]),
// P = zero-padded gt. Row index cy0+1 in [0,129], col cx0+1 in [0,257].
constexpr int QH = HI + 2;
constexpr int QW = WI + 2;
constexpr size_t QIMG = (size_t)QH * QW;           // quads per image

__global__ __launch_bounds__(256) void pad4_kernel(
    const float* __restrict__ gt, vfloat4* __restrict__ Q)
{
    const int i = blockIdx.x * 256 + threadIdx.x;  // over BATCH*QIMG
    if (i >= (int)(BATCH * QIMG)) return;
    const int b = i / (int)QIMG;
    const int r = i - b * (int)QIMG;
    const int y = r / QW - 1;                      // [-1, HI]
    const int x = r - (r / QW) * QW - 1;           // [-1, WI]
    const float* __restrict__ g = gt + (size_t)b * (HI * WI);
    auto val = [&](int yy, int xx) -> float {
        return (yy >= 0 && yy < HI && xx >= 0 && xx < WI)
                   ? g[yy * WI + xx] : 0.0f;
    };
    vfloat4 q = { val(y, x), val(y, x + 1), val(y + 1, x), val(y + 1, x + 1) };
    Q[i] = q;
}

__global__ __launch_bounds__(256) void stn_kernel(
    const float* __restrict__ gt,     // [B, HI, WI] (boxy path)
    const float* __restrict__ theta,  // [B, 6]
    const vfloat4* __restrict__ Q,    // quad images in d_ws
    float* __restrict__ out)          // [2, B, HO, WO] f32
{
    const int row = blockIdx.x;            // b*HO + h
    const int b = row >> 10;
    const int h = row & (HO - 1);
    const int t = threadIdx.x;

    const float* tb = theta + b * 6;
    const float t0 = tb[0], t1 = tb[1], t2 = tb[2];
    const float t3 = tb[3], t4 = tb[4], t5 = tb[5];
    const float* __restrict__ gtb = gt + b * (HI * WI);
    // Pre-offset so index is cy0*QW + cx0 (pad ring at cy0=-1 / cx0=-1 ok).
    const vfloat4* __restrict__ Qb = Q + (size_t)b * QIMG + QW + 1;

    const float ys = (h + 0.5f) * (2.0f / (float)HO) - 1.0f;
    const float dix = t0;
    const float diy = 0.5f * t3;

    // boxy y-blend pieces (uniform over the row, independent of column):
    const float gy2 = t4 * ys + t5;
    const float iyy = ((gy2 + 1.0f) * (float)HO - 1.0f) * 0.5f;
    const float fyy = floorf(iyy);
    const float wyy = iyy - fyy;
    const float vy0 = (fyy >= 0.0f && fyy <= (float)(HO - 1)) ? 1.0f : 0.0f;
    const float vy1 = (fyy >= -1.0f && fyy <= (float)(HO - 2)) ? 1.0f : 0.0f;
    const int y0 = ((int)fminf(fmaxf(fyy,        0.0f), (float)(HO - 1))) >> 3;
    const int y1 = ((int)fminf(fmaxf(fyy + 1.0f, 0.0f), (float)(HO - 1))) >> 3;
    const float wA = (1.0f - wyy) * vy0;
    const float wB = wyy * vy1;

    float* const outrow  = out + (size_t)row * WO;
    float* const outrowy = out + NPIX + (size_t)row * WO;

#pragma unroll
    for (int s = 0; s < 2; ++s) {
        const int w0s = (s << 10) + (t << 2);   // 4-px segment base column

        // ---- boxy: one scalar per 4-px group (group never straddles a cell) ----
        {
            const int cell = w0s >> 3;
            const float s0 = gtb[y0 * WI + cell];
            const float s1 = gtb[y1 * WI + cell];
            const float byv = s0 * wA + s1 * wB;
            const vfloat4 vb = {byv, byv, byv, byv};
            *reinterpret_cast<vfloat4*>(outrowy + w0s) = vb;   // 1KB/wave contiguous
        }

        // ---- box: 4 px bilinear via one quad load each ----
        const float xn0 = (w0s + 0.5f) * (2.0f / (float)WO) - 1.0f;
        const float gx0 = t0 * xn0 + (t1 * ys + t2);
        const float gy0 = t3 * xn0 + (t4 * ys + t5);
        const float ix0 = ((gx0 + 1.0f) * (float)WO - 1.0f) * 0.5f;
        const float iy0 = ((gy0 + 1.0f) * (float)HO - 1.0f) * 0.5f;

        const float ixe = ix0 + 3.0f * dix;
        const float iye = iy0 + 3.0f * diy;
        const float ixmin = fminf(ix0, ixe), ixmax = fmaxf(ix0, ixe);
        const float iymin = fminf(iy0, iye), iymax = fmaxf(iy0, iye);
        const bool segzero = (ixmax < -1.0f) || (ixmin >= (float)WO) ||
                             (iymax < -1.0f) || (iymin >= (float)HO);
        const bool segsafe = (ixmin >= -1.0f) && (ixmax < (float)WO) &&
                             (iymin >= -1.0f) && (iymax < (float)HO);

        float px[4];
        if (segzero) {
#pragma unroll
            for (int p = 0; p < 4; ++p) px[p] = 0.0f;
        } else if (segsafe) {
            // No clamps: xi in [-1, WO-1], shifts land in [-1,WI]/[-1,HI];
            // pad ring supplies zeros.
            vfloat4 q[4];
            float wx[4], wy[4];
            bool cxe[4], cye[4];
#pragma unroll
            for (int p = 0; p < 4; ++p) {
                const float ixp = fmaf((float)p, dix, ix0);
                const float iyp = fmaf((float)p, diy, iy0);
                const float fx = floorf(ixp), fy = floorf(iyp);
                wx[p] = ixp - fx;  wy[p] = iyp - fy;
                const int xi = (int)fx, yi = (int)fy;
                const int cx0 = xi >> 3;
                const int cx1 = (xi + 1) >> 3;
                const int cy0 = yi >> 3;
                const int cy1 = (yi + 1) >> 3;
                cxe[p] = (cx1 == cx0);
                cye[p] = (cy1 == cy0);
                q[p] = Qb[cy0 * QW + cx0];
            }
#pragma unroll
            for (int p = 0; p < 4; ++p) {
                const float a  = q[p].x;
                const float bb = cxe[p] ? q[p].x : q[p].y;   // P[cy0][cx1]
                const float c  = cye[p] ? q[p].x : q[p].z;   // P[cy1][cx0]
                const float dl = cxe[p] ? q[p].z : q[p].w;
                const float d  = cye[p] ? bb     : dl;       // P[cy1][cx1]
                const float h0 = fmaf(wx[p], bb - a, a);
                const float h1 = fmaf(wx[p], d - c,  c);
                px[p] = fmaf(wy[p], h1 - h0, h0);
            }
        } else {
            // General clamped path (segment straddles a boundary) — r12 logic.
            float ix = ix0, iy = iy0;
#pragma unroll
            for (int p = 0; p < 4; ++p) {
                const float fx = floorf(ix), fy = floorf(iy);
                const float wx = ix - fx,    wy = iy - fy;
                const int xi = (int)fx, yi = (int)fy;    // cvt saturates at extremes
                const int cx0 = min(max(xi >> 3,       -1), WI);
                const int cx1 = min(max((xi + 1) >> 3, -1), WI);
                const int cy0 = min(max(yi >> 3,       -1), HI);
                const int cy1 = min(max((yi + 1) >> 3, -1), HI);
                const vfloat4 q = Qb[cy0 * QW + cx0];
                const bool cxe = (cx1 == cx0);
                const bool cye = (cy1 == cy0);
                const float a  = q.x;
                const float bb = cxe ? q.x : q.y;        // P[cy0][cx1]
                const float c  = cye ? q.x : q.z;        // P[cy1][cx0]
                const float dl = cxe ? q.z : q.w;
                const float d  = cye ? bb  : dl;         // P[cy1][cx1]
                const float h0 = fmaf(wx, bb - a, a);
                const float h1 = fmaf(wx, d - c,  c);
                px[p] = fmaf(wy, h1 - h0, h0);
                ix += dix; iy += diy;
            }
        }
        const vfloat4 v = {px[0], px[1], px[2], px[3]};
        *reinterpret_cast<vfloat4*>(outrow + w0s) = v;        // 1KB/wave contiguous
    }
}

extern "C" void kernel_launch(void* const* d_in, const int* in_sizes, int n_in,
                              void* d_out, int out_size, void* d_ws, size_t ws_size,
                              hipStream_t stream) {
    const float* gt    = (const float*)d_in[0];
    const float* theta = (const float*)d_in[1];
    float* out = (float*)d_out;
    vfloat4* Q = (vfloat4*)d_ws;   // 8*130*258*16 B ~= 4.3 MB << ws_size

    const int qN = (int)(BATCH * QIMG);
    pad4_kernel<<<(qN + 255) / 256, 256, 0, stream>>>(gt, Q);
    stn_kernel<<<BATCH * HO, 256, 0, stream>>>(gt, theta, Q, out);
}